// Round 21
// baseline (306.381 us; speedup 1.0000x reference)
//
#include <hip/hip_runtime.h>
#include <cfloat>

// z:   [16, 64, 32, 32] f32 -> N = 16384 rows of dim 64 (row n = b*1024 + hw)
// emb: [8192, 64] f32
// out (f32): quantized [1048576] | loss [1] | entropy_aux [1] | min_indices [16384]
//
// s = z.e via 4-term bf16-split MFMA (zh+zl)(eh+el), f32 accumulate (pass 1);
// pass 2 uses 3 terms (zl*el ~ 4e-9 rms, only feeds codebook entropy).
// argmin on numpy-rounding-emulated d = fl(fl(zz+ee) - 2s) (2s exact).
// Row-reduction fused into pass1 (per-panel semaphore); finalize fused into quant.

typedef __attribute__((ext_vector_type(8))) short short8v;   // 8 bf16
typedef __attribute__((ext_vector_type(4))) float f32x4;

#define C100L2E 144.26950408889634f   // 100*log2(e)
#define C200L2E 288.53900817779268f   // 200*log2(e)
#define LN2 0.6931471805599453

// ws layout (bytes):
#define BLOB_TILE 33792               // 16K hi bf16 + 16K lo bf16 + 512B e2 + 512B c2
#define OFF_BLOB   0                  // 64 tiles * 33792 = 2162688
#define OFF_INVZ   2162688            // f32[16384]
#define OFF_MINIDX 2228224            // i32[16384]
#define OFF_AVG    2293760            // f32[8192]   (zeroed each launch)
#define OFF_PSE    2326528            // double      (zeroed each launch)
#define OFF_SEM    2326544            // i32[129]    (zeroed each launch; pad 1024)
#define OFF_ZPART  2327568            // f32[4][16384]
#define OFF_S1PART (OFF_ZPART + 262144)
#define OFF_DMPART (OFF_S1PART + 262144)
#define OFF_IMPART (OFF_DMPART + 262144)
#define OFF_LOSSP  (OFF_IMPART + 262144)  // dbl[1024] fully rewritten each launch
#define OFF_ZZ     (OFF_LOSSP + 32768)    // f32[16384] numpy-pairwise ||z||^2

__device__ __forceinline__ unsigned short f2bf_rne(float f) {
    unsigned u = __float_as_uint(f);
    u = (u + 0x7fffu + ((u >> 16) & 1u)) >> 16;
    return (unsigned short)u;
}

__device__ __forceinline__ void gload_lds16(const void* g, void* l) {
    __builtin_amdgcn_global_load_lds(
        (const __attribute__((address_space(1))) unsigned int*)g,
        (__attribute__((address_space(3))) unsigned int*)l, 16, 0, 0);
}

// Merged prep: blocks 0..31 build emb tile images (+e2 +c2), blocks 32..95
// build the z A-fragment blob + numpy-pairwise ||z||^2.
__global__ __launch_bounds__(256) void k_prep(
    const float* __restrict__ emb, const float* __restrict__ z,
    char* __restrict__ blob, char* __restrict__ zblob, float* __restrict__ zz)
{
    if (blockIdx.x < 32) {
        const int k = blockIdx.x * 256 + threadIdx.x;   // 8192 emb rows
        const float* row = emb + k * 64;
        float fv[64];
#pragma unroll
        for (int i = 0; i < 16; ++i) {
            float4 v = ((const float4*)row)[i];
            fv[4 * i] = v.x; fv[4 * i + 1] = v.y; fv[4 * i + 2] = v.z; fv[4 * i + 3] = v.w;
        }
        float r8[8];
#pragma unroll
        for (int j = 0; j < 8; ++j) r8[j] = __fmul_rn(fv[j], fv[j]);
#pragma unroll
        for (int i = 8; i < 64; i += 8)
#pragma unroll
            for (int j = 0; j < 8; ++j)
                r8[j] = __fadd_rn(r8[j], __fmul_rn(fv[i + j], fv[i + j]));
        float s01 = __fadd_rn(r8[0], r8[1]), s23 = __fadd_rn(r8[2], r8[3]);
        float s45 = __fadd_rn(r8[4], r8[5]), s67 = __fadd_rn(r8[6], r8[7]);
        float e2 = __fadd_rn(__fadd_rn(s01, s23), __fadd_rn(s45, s67));

        char* tb = blob + (size_t)(k >> 7) * BLOB_TILE;
        const int r = k & 127;
        ((float*)(tb + 32768))[r] = e2;
        ((float*)(tb + 33280))[r] = e2 * C100L2E;   // precomputed c2
        const int sw = (r & 7) << 4;
#pragma unroll
        for (int dh = 0; dh < 2; ++dh)
#pragma unroll
            for (int cg = 0; cg < 4; ++cg) {
                short8v hv, lv;
#pragma unroll
                for (int e = 0; e < 8; ++e) {
                    float f = fv[dh * 32 + cg * 8 + e];
                    unsigned short hb = f2bf_rne(f);
                    float hf = __uint_as_float((unsigned)hb << 16);
                    hv[e] = (short)hb;
                    lv[e] = (short)f2bf_rne(f - hf);
                }
                const int byt = (r * 128 + dh * 64 + cg * 16) ^ sw;
                *(short8v*)(tb + byt) = hv;
                *(short8v*)(tb + 16384 + byt) = lv;
            }
    } else {
        const int r = (blockIdx.x - 32) * 256 + threadIdx.x;   // 16384 z rows
        const float* src = z + (r >> 10) * 65536 + (r & 1023);
        float fv[64];
#pragma unroll
        for (int c = 0; c < 64; ++c) fv[c] = src[c * 1024];

        float r8[8];
#pragma unroll
        for (int j = 0; j < 8; ++j) r8[j] = __fmul_rn(fv[j], fv[j]);
#pragma unroll
        for (int i = 8; i < 64; i += 8)
#pragma unroll
            for (int j = 0; j < 8; ++j)
                r8[j] = __fadd_rn(r8[j], __fmul_rn(fv[i + j], fv[i + j]));
        float s01 = __fadd_rn(r8[0], r8[1]), s23 = __fadd_rn(r8[2], r8[3]);
        float s45 = __fadd_rn(r8[4], r8[5]), s67 = __fadd_rn(r8[6], r8[7]);
        zz[r] = __fadd_rn(__fadd_rn(s01, s23), __fadd_rn(s45, s67));

        char* tb = zblob + (size_t)(r >> 6) * 16384;
        const int rowp = r & 63;
#pragma unroll
        for (int cg = 0; cg < 8; ++cg) {
            short8v hv, lv;
#pragma unroll
            for (int e = 0; e < 8; ++e) {
                float f = fv[cg * 8 + e];
                unsigned short hb = f2bf_rne(f);
                float hf = __uint_as_float((unsigned)hb << 16);
                hv[e] = (short)hb;
                lv[e] = (short)f2bf_rne(f - hf);
            }
            *(short8v*)(tb + rowp * 128 + cg * 16) = hv;
            *(short8v*)(tb + 8192 + rowp * 128 + cg * 16) = lv;
        }
    }
}

// stage one 33.8KB emb tile image into LDS, 256-thread version (pass 2)
#define STAGE_EMB(DSTBASE, TILE)                                                  \
    {                                                                             \
        const char* gsrc = blob + (size_t)(TILE) * BLOB_TILE;                     \
        char* ldst = (DSTBASE) + ((tid >> 6) << 10);                              \
        const char* g = gsrc + tid * 16;                                          \
        _Pragma("unroll")                                                         \
        for (int q = 0; q < 8; ++q)                                               \
            gload_lds16(g + q * 4096, ldst + q * 4096);                           \
        if (tid < 64) gload_lds16(gsrc + 32768 + (tid & 63) * 16,                 \
                                  (DSTBASE) + 32768);                             \
    }

// 512-thread version (pass 1): each wave stages its 4KB chunk
#define STAGE512(DSTBASE, TILE)                                                   \
    {                                                                             \
        const char* gsrc = blob + (size_t)(TILE) * BLOB_TILE;                     \
        char* ldst = (DSTBASE) + ((tid >> 6) << 12);                              \
        const char* g = gsrc + ((tid >> 6) << 12) + (tid & 63) * 16;              \
        _Pragma("unroll")                                                         \
        for (int q = 0; q < 4; ++q)                                               \
            gload_lds16(g + q * 1024, ldst + q * 1024);                           \
        if (tid < 64) gload_lds16(gsrc + 32768 + (tid & 63) * 16,                 \
                                  (DSTBASE) + 32768);                             \
    }

// ---- pass 1 (hot loop frozen): 8 waves x 16 rows, dbuf, 1 barrier/iter.
// Tail: per-panel semaphore; 4th-arriving block inlines the row reduction.
__global__ __launch_bounds__(512) void k_pass1(
    const char* __restrict__ zblob, const char* __restrict__ blob,
    const float* __restrict__ zz,
    float* __restrict__ Zpart, float* __restrict__ S1part,
    float* __restrict__ dmpart, int* __restrict__ impart,
    int* __restrict__ sem, float* __restrict__ invZ,
    int* __restrict__ minidx, float* __restrict__ out_idx,
    double* __restrict__ pse_sum)
{
    __shared__ __align__(16) char smem[2 * BLOB_TILE];
    __shared__ int islast;

    const int tid = threadIdx.x;
    const int panel = blockIdx.x >> 2;      // 128 panels x 128 rows
    const int ks = blockIdx.x & 3;
    const int n0 = panel * 128;

    const int ln = tid & 63, wv = tid >> 6;
    const int lr = ln & 15, lg = ln >> 4;

    short8v Ah[2], Al[2];
    {
        const int p64 = (n0 >> 6) + (wv >> 2);
        const int rowp = (wv & 3) * 16 + lr;
        const char* tb = zblob + (size_t)p64 * 16384;
#pragma unroll
        for (int s = 0; s < 2; ++s) {
            const int byt = rowp * 128 + s * 64 + lg * 16;
            Ah[s] = *(const short8v*)(tb + byt);
            Al[s] = *(const short8v*)(tb + 8192 + byt);
        }
    }
    float zzr[4];
#pragma unroll
    for (int rg = 0; rg < 4; ++rg)
        zzr[rg] = zz[n0 + wv * 16 + lg * 4 + rg];

    STAGE512(smem, ks * 16);    // prologue: stage tile 0 into buf 0

    float Zp[4] = {0.f, 0.f, 0.f, 0.f}, S1p[4] = {0.f, 0.f, 0.f, 0.f};
    float dmin[4] = {FLT_MAX, FLT_MAX, FLT_MAX, FLT_MAX};
    int imin[4] = {0, 0, 0, 0};

    for (int it = 0; it < 16; ++it) {
        const int kbase = ks * 2048 + it * 128;
        __syncthreads();   // buf[it&1] staged (vmcnt drained before barrier)
        const char* bb = smem + (it & 1) * BLOB_TILE;
        if (it < 15) STAGE512(smem + ((it + 1) & 1) * BLOB_TILE, ks * 16 + it + 1);

        f32x4 acc[8];
#pragma unroll
        for (int f = 0; f < 8; ++f) { f32x4 zv = {0.f, 0.f, 0.f, 0.f}; acc[f] = zv; }

#pragma unroll
        for (int f = 0; f < 8; ++f) {
            const int rr = f * 16 + lr;
            const int sw2 = (rr & 7) << 4;
            short8v Bh[2], Bl[2];
#pragma unroll
            for (int s = 0; s < 2; ++s) {
                const int byt = (rr * 128 + s * 64 + lg * 16) ^ sw2;
                Bh[s] = *(const short8v*)(bb + byt);
                Bl[s] = *(const short8v*)(bb + 16384 + byt);
            }
#pragma unroll
            for (int s = 0; s < 2; ++s) {
                acc[f] = __builtin_amdgcn_mfma_f32_16x16x32_bf16(Ah[s], Bh[s], acc[f], 0, 0, 0);
                acc[f] = __builtin_amdgcn_mfma_f32_16x16x32_bf16(Ah[s], Bl[s], acc[f], 0, 0, 0);
                acc[f] = __builtin_amdgcn_mfma_f32_16x16x32_bf16(Al[s], Bh[s], acc[f], 0, 0, 0);
                acc[f] = __builtin_amdgcn_mfma_f32_16x16x32_bf16(Al[s], Bl[s], acc[f], 0, 0, 0);
            }
        }

#pragma unroll
        for (int f = 0; f < 8; ++f) {
            const float e2v = *(const float*)(bb + 32768 + (f * 16 + lr) * 4);
            const float c2 = *(const float*)(bb + 33280 + (f * 16 + lr) * 4);
            const int kk = kbase + f * 16 + lr;
#pragma unroll
            for (int rg = 0; rg < 4; ++rg) {
                const float sdot = acc[f][rg];
                const float t = fmaf(sdot, C200L2E, -c2);
                const float ex = __builtin_amdgcn_exp2f(t);
                Zp[rg] += ex;
                S1p[rg] = fmaf(t, ex, S1p[rg]);
                const float pre = __fadd_rn(zzr[rg], e2v);
                const float dnp = fmaf(-2.f, sdot, pre);
                if (dnp < dmin[rg]) { dmin[rg] = dnp; imin[rg] = kk; }
            }
        }
    }

    // reduce across the 16 lr lanes; lex tiebreak (min d, then min idx)
#pragma unroll
    for (int msk = 1; msk < 16; msk <<= 1) {
#pragma unroll
        for (int rg = 0; rg < 4; ++rg) {
            float d2 = __shfl_xor(dmin[rg], msk, 16);
            int i2 = __shfl_xor(imin[rg], msk, 16);
            float Z2 = __shfl_xor(Zp[rg], msk, 16);
            float s2 = __shfl_xor(S1p[rg], msk, 16);
            if (d2 < dmin[rg] || (d2 == dmin[rg] && i2 < imin[rg])) {
                dmin[rg] = d2; imin[rg] = i2;
            }
            Zp[rg] += Z2;
            S1p[rg] += s2;
        }
    }
    if (lr == 0) {
#pragma unroll
        for (int rg = 0; rg < 4; ++rg) {
            const int n = n0 + wv * 16 + lg * 4 + rg;
            Zpart[ks * 16384 + n] = Zp[rg];
            S1part[ks * 16384 + n] = S1p[rg];
            dmpart[ks * 16384 + n] = dmin[rg];
            impart[ks * 16384 + n] = imin[rg];
        }
    }

    // --- per-panel completion: 4th-arriving block inlines the row reduction ---
    __threadfence();     // release this block's part-writes
    __syncthreads();
    if (tid == 0) {
        int old = atomicAdd(&sem[panel], 1);
        islast = (old == 3) ? 1 : 0;
    }
    __syncthreads();
    if (islast) {
        __threadfence();  // acquire: see the other 3 blocks' part-writes
        if (tid < 128) {
            const int n = n0 + tid;
            float Z = __fadd_rn(__fadd_rn(Zpart[n], Zpart[16384 + n]),
                                __fadd_rn(Zpart[32768 + n], Zpart[49152 + n]));
            float S1 = __fadd_rn(__fadd_rn(S1part[n], S1part[16384 + n]),
                                 __fadd_rn(S1part[32768 + n], S1part[49152 + n]));
            float dm = dmpart[n];
            int im = impart[n];
#pragma unroll
            for (int ksp = 1; ksp < 4; ++ksp) {
                float d2 = dmpart[ksp * 16384 + n];
                int i2 = impart[ksp * 16384 + n];
                if (d2 < dm || (d2 == dm && i2 < im)) { dm = d2; im = i2; }
            }
            minidx[n] = im;
            out_idx[n] = (float)im;
            float iz = 1.0f / Z;
            invZ[n] = iz;
            double h = log((double)Z) - LN2 * (double)S1 * (double)iz;
#pragma unroll
            for (int m = 32; m > 0; m >>= 1) h += __shfl_xor(h, m, 64);
            if ((tid & 63) == 0) atomicAdd(pse_sum, h);
        }
    }
}

// ---- pass 2 v7 (k-major, m=1): block = k-tile kt (128 codes) x 1024-row n
// range; wave owns 16 rows/iter, 16 iters; acc[8] + per-lane acck register
// accumulation; 3-term MFMA; one shfl+atomic round at the end.
__global__ __launch_bounds__(256) void k_pass2(
    const char* __restrict__ zblob, const char* __restrict__ blob,
    const float* __restrict__ invZ, float* __restrict__ avg_acc)
{
    __shared__ __align__(16) char smem[BLOB_TILE + 4096];
    float* izAll = (float*)(smem + BLOB_TILE);   // [1024] f32

    const int tid = threadIdx.x;
    const int kt = blockIdx.x & 63;
    const int ns = blockIdx.x >> 6;      // 0..15: rows ns*1024 .. +1023
    const int ln = tid & 63, wv = tid >> 6;
    const int lr = ln & 15, lg = ln >> 4;

    STAGE_EMB(smem, kt);
    gload_lds16((const char*)(invZ + ns * 1024) + tid * 16,
                (char*)izAll + (wv << 10));
    __syncthreads();     // only barrier in the kernel

    float c2v[8];
#pragma unroll
    for (int f = 0; f < 8; ++f)
        c2v[f] = *(const float*)(smem + 33280 + (f * 16 + lr) * 4);

    float acck[8] = {0.f, 0.f, 0.f, 0.f, 0.f, 0.f, 0.f, 0.f};

#pragma unroll 1
    for (int it = 0; it < 16; ++it) {
        const char* tb = zblob + (size_t)(ns * 16 + it) * 16384;
        const int rowp = wv * 16 + lr;
        short8v Ah[2], Al[2];
#pragma unroll
        for (int s = 0; s < 2; ++s) {
            const int byt = rowp * 128 + s * 64 + lg * 16;
            Ah[s] = *(const short8v*)(tb + byt);
            Al[s] = *(const short8v*)(tb + 8192 + byt);
        }
        float4 iz = *(const float4*)&izAll[it * 64 + wv * 16 + lg * 4];
        float izr[4] = {iz.x, iz.y, iz.z, iz.w};

        f32x4 acc[8];
#pragma unroll
        for (int f = 0; f < 8; ++f) { f32x4 zv = {0.f, 0.f, 0.f, 0.f}; acc[f] = zv; }

#pragma unroll
        for (int f = 0; f < 8; ++f) {
            const int rr = f * 16 + lr;
            const int sw2 = (rr & 7) << 4;
            short8v Bh[2], Bl[2];
#pragma unroll
            for (int s = 0; s < 2; ++s) {
                const int byt = (rr * 128 + s * 64 + lg * 16) ^ sw2;
                Bh[s] = *(const short8v*)(smem + byt);
                Bl[s] = *(const short8v*)(smem + 16384 + byt);
            }
#pragma unroll
            for (int s = 0; s < 2; ++s) {
                acc[f] = __builtin_amdgcn_mfma_f32_16x16x32_bf16(Ah[s], Bh[s], acc[f], 0, 0, 0);
                acc[f] = __builtin_amdgcn_mfma_f32_16x16x32_bf16(Ah[s], Bl[s], acc[f], 0, 0, 0);
                acc[f] = __builtin_amdgcn_mfma_f32_16x16x32_bf16(Al[s], Bh[s], acc[f], 0, 0, 0);
            }
        }

#pragma unroll
        for (int f = 0; f < 8; ++f) {
#pragma unroll
            for (int rg = 0; rg < 4; ++rg) {
                const float t = fmaf(acc[f][rg], C200L2E, -c2v[f]);
                const float ex = __builtin_amdgcn_exp2f(t);
                acck[f] = fmaf(ex, izr[rg], acck[f]);
            }
        }
    }

#pragma unroll
    for (int f = 0; f < 8; ++f) {
        float cs = acck[f];
        cs += __shfl_xor(cs, 16, 64);
        cs += __shfl_xor(cs, 32, 64);
        if (lg == 0) atomicAdd(&avg_acc[kt * 128 + f * 16 + lr], cs);
    }
}

// gather quantized output + per-block loss partial; 4 elements/thread.
// Last-finishing block inlines the scalar finalize (loss + entropy_aux).
__global__ __launch_bounds__(256) void k_quant(
    const float* __restrict__ z, const float* __restrict__ emb,
    const int* __restrict__ minidx, float* __restrict__ out,
    double* __restrict__ loss_part, const float* __restrict__ avg_acc,
    const double* __restrict__ pse_sum, int* __restrict__ sem)
{
    __shared__ float lred[4];
    __shared__ double red[256];
    __shared__ int islast;
    const int tid = threadIdx.x;
    const int o4 = (blockIdx.x * 256 + tid) * 4;
    const int nb = ((o4 >> 16) << 10) + (o4 & 1023);
    const int c = (o4 >> 10) & 63;
    const float4 zv = *(const float4*)(z + o4);
    const int i0 = minidx[nb], i1 = minidx[nb + 1];
    const int i2 = minidx[nb + 2], i3 = minidx[nb + 3];
    float4 ev;
    ev.x = emb[i0 * 64 + c];
    ev.y = emb[i1 * 64 + c];
    ev.z = emb[i2 * 64 + c];
    ev.w = emb[i3 * 64 + c];
    *(float4*)(out + o4) = ev;
    const float dx = ev.x - zv.x, dy = ev.y - zv.y;
    const float dz = ev.z - zv.z, dw = ev.w - zv.w;
    float sq = dx * dx + dy * dy + dz * dz + dw * dw;
#pragma unroll
    for (int m = 32; m > 0; m >>= 1) sq += __shfl_xor(sq, m, 64);
    if ((tid & 63) == 0) lred[tid >> 6] = sq;
    __syncthreads();
    if (tid == 0) {
        loss_part[blockIdx.x] = (double)lred[0] + (double)lred[1]
                              + (double)lred[2] + (double)lred[3];
        __threadfence();
        int old = atomicAdd(&sem[128], 1);
        islast = (old == 1023) ? 1 : 0;
    }
    __syncthreads();
    if (!islast) return;
    __threadfence();   // acquire: see all blocks' loss_part writes

    double lsum = 0.0;
    for (int k = tid; k < 1024; k += 256) lsum += loss_part[k];
    red[tid] = lsum;
    __syncthreads();
    for (int s = 128; s > 0; s >>= 1) {
        if (tid < s) red[tid] += red[tid + s];
        __syncthreads();
    }
    double ltot = red[0];
    __syncthreads();

    double local = 0.0;
    for (int k = tid; k < 8192; k += 256) {
        float p = avg_acc[k] * (1.0f / 16384.0f);
        float cl = fmaxf(p, 1e-5f);
        local += (double)(-p * logf(cl));
    }
    red[tid] = local;
    __syncthreads();
    for (int s = 128; s > 0; s >>= 1) {
        if (tid < s) red[tid] += red[tid + s];
        __syncthreads();
    }
    if (tid == 0) {
        double ce = red[0];
        double pse = pse_sum[0] / 16384.0;
        out[1048576] = (float)(1.25 * ltot / 1048576.0);
        out[1048577] = (float)(pse - ce);
    }
}

extern "C" void kernel_launch(void* const* d_in, const int* in_sizes, int n_in,
                              void* d_out, int out_size, void* d_ws, size_t ws_size,
                              hipStream_t stream) {
    const float* z = (const float*)d_in[0];
    const float* emb = (const float*)d_in[1];
    float* out = (float*)d_out;
    char* ws = (char*)d_ws;
    char* blob = ws + OFF_BLOB;
    float* invZ = (float*)(ws + OFF_INVZ);
    int* minidx = (int*)(ws + OFF_MINIDX);
    float* avg_acc = (float*)(ws + OFF_AVG);
    double* pse_sum = (double*)(ws + OFF_PSE);
    int* sem = (int*)(ws + OFF_SEM);
    float* Zpart = (float*)(ws + OFF_ZPART);
    float* S1part = (float*)(ws + OFF_S1PART);
    float* dmpart = (float*)(ws + OFF_DMPART);
    int* impart = (int*)(ws + OFF_IMPART);
    double* loss_part = (double*)(ws + OFF_LOSSP);
    float* zz = (float*)(ws + OFF_ZZ);
    // z_blob scratch lives in d_out's quantized region (exactly 4 MB);
    // k_quant overwrites it afterwards (stream-ordered).
    char* zblob = (char*)d_out;

    // zero avg_acc + pse_sum + semaphores every launch (no cross-replay state)
    hipMemsetAsync(ws + OFF_AVG, 0, 32768 + 16 + 1024, stream);

    k_prep<<<96, 256, 0, stream>>>(emb, z, blob, zblob, zz);
    k_pass1<<<512, 512, 0, stream>>>(zblob, blob, zz, Zpart, S1part, dmpart, impart,
                                     sem, invZ, minidx, out + 1048578, pse_sum);
    k_pass2<<<1024, 256, 0, stream>>>(zblob, blob, invZ, avg_acc);
    k_quant<<<1024, 256, 0, stream>>>(z, emb, minidx, out, loss_part,
                                      avg_acc, pse_sum, sem);
}

// Round 22
// 168.154 us; speedup vs baseline: 1.8220x; 1.8220x over previous
//
#include <hip/hip_runtime.h>
#include <cfloat>

// z:   [16, 64, 32, 32] f32 -> N = 16384 rows of dim 64 (row n = b*1024 + hw)
// emb: [8192, 64] f32
// out (f32): quantized [1048576] | loss [1] | entropy_aux [1] | min_indices [16384]
//
// s = z.e via 4-term bf16-split MFMA (zh+zl)(eh+el), f32 accumulate (pass 1);
// pass 2 uses 3 terms (zl*el ~ 4e-9 rms, only feeds codebook entropy).
// argmin on numpy-rounding-emulated d = fl(fl(zz+ee) - 2s) (2s exact).

typedef __attribute__((ext_vector_type(8))) short short8v;   // 8 bf16
typedef __attribute__((ext_vector_type(4))) float f32x4;

#define C100L2E 144.26950408889634f   // 100*log2(e)
#define C200L2E 288.53900817779268f   // 200*log2(e)
#define LN2 0.6931471805599453

// ws layout (bytes):
#define BLOB_TILE 33792               // 16K hi bf16 + 16K lo bf16 + 512B e2 + 512B c2
#define OFF_BLOB   0                  // 64 tiles * 33792 = 2162688
#define OFF_INVZ   2162688            // f32[16384]
#define OFF_MINIDX 2228224            // i32[16384]
#define OFF_AVG    2293760            // f32[8192]   (zeroed each launch)
#define OFF_PSE    2326528            // double      (zeroed each launch)
#define OFF_ZPART  2326544            // f32[4][16384]
#define OFF_S1PART (OFF_ZPART + 262144)
#define OFF_DMPART (OFF_S1PART + 262144)
#define OFF_IMPART (OFF_DMPART + 262144)
#define OFF_LOSSP  (OFF_IMPART + 262144)  // dbl[1024] fully rewritten each launch
#define OFF_ZZ     (OFF_LOSSP + 32768)    // f32[16384] numpy-pairwise ||z||^2

__device__ __forceinline__ unsigned short f2bf_rne(float f) {
    unsigned u = __float_as_uint(f);
    u = (u + 0x7fffu + ((u >> 16) & 1u)) >> 16;
    return (unsigned short)u;
}

__device__ __forceinline__ void gload_lds16(const void* g, void* l) {
    __builtin_amdgcn_global_load_lds(
        (const __attribute__((address_space(1))) unsigned int*)g,
        (__attribute__((address_space(3))) unsigned int*)l, 16, 0, 0);
}

// Merged prep: blocks 0..31 build emb tile images (+e2 +c2), blocks 32..95
// build the z A-fragment blob + numpy-pairwise ||z||^2.
__global__ __launch_bounds__(256) void k_prep(
    const float* __restrict__ emb, const float* __restrict__ z,
    char* __restrict__ blob, char* __restrict__ zblob, float* __restrict__ zz)
{
    if (blockIdx.x < 32) {
        const int k = blockIdx.x * 256 + threadIdx.x;   // 8192 emb rows
        const float* row = emb + k * 64;
        float fv[64];
#pragma unroll
        for (int i = 0; i < 16; ++i) {
            float4 v = ((const float4*)row)[i];
            fv[4 * i] = v.x; fv[4 * i + 1] = v.y; fv[4 * i + 2] = v.z; fv[4 * i + 3] = v.w;
        }
        float r8[8];
#pragma unroll
        for (int j = 0; j < 8; ++j) r8[j] = __fmul_rn(fv[j], fv[j]);
#pragma unroll
        for (int i = 8; i < 64; i += 8)
#pragma unroll
            for (int j = 0; j < 8; ++j)
                r8[j] = __fadd_rn(r8[j], __fmul_rn(fv[i + j], fv[i + j]));
        float s01 = __fadd_rn(r8[0], r8[1]), s23 = __fadd_rn(r8[2], r8[3]);
        float s45 = __fadd_rn(r8[4], r8[5]), s67 = __fadd_rn(r8[6], r8[7]);
        float e2 = __fadd_rn(__fadd_rn(s01, s23), __fadd_rn(s45, s67));

        char* tb = blob + (size_t)(k >> 7) * BLOB_TILE;
        const int r = k & 127;
        ((float*)(tb + 32768))[r] = e2;
        ((float*)(tb + 33280))[r] = e2 * C100L2E;   // precomputed c2
        const int sw = (r & 7) << 4;
#pragma unroll
        for (int dh = 0; dh < 2; ++dh)
#pragma unroll
            for (int cg = 0; cg < 4; ++cg) {
                short8v hv, lv;
#pragma unroll
                for (int e = 0; e < 8; ++e) {
                    float f = fv[dh * 32 + cg * 8 + e];
                    unsigned short hb = f2bf_rne(f);
                    float hf = __uint_as_float((unsigned)hb << 16);
                    hv[e] = (short)hb;
                    lv[e] = (short)f2bf_rne(f - hf);
                }
                const int byt = (r * 128 + dh * 64 + cg * 16) ^ sw;
                *(short8v*)(tb + byt) = hv;
                *(short8v*)(tb + 16384 + byt) = lv;
            }
    } else {
        const int r = (blockIdx.x - 32) * 256 + threadIdx.x;   // 16384 z rows
        const float* src = z + (r >> 10) * 65536 + (r & 1023);
        float fv[64];
#pragma unroll
        for (int c = 0; c < 64; ++c) fv[c] = src[c * 1024];

        float r8[8];
#pragma unroll
        for (int j = 0; j < 8; ++j) r8[j] = __fmul_rn(fv[j], fv[j]);
#pragma unroll
        for (int i = 8; i < 64; i += 8)
#pragma unroll
            for (int j = 0; j < 8; ++j)
                r8[j] = __fadd_rn(r8[j], __fmul_rn(fv[i + j], fv[i + j]));
        float s01 = __fadd_rn(r8[0], r8[1]), s23 = __fadd_rn(r8[2], r8[3]);
        float s45 = __fadd_rn(r8[4], r8[5]), s67 = __fadd_rn(r8[6], r8[7]);
        zz[r] = __fadd_rn(__fadd_rn(s01, s23), __fadd_rn(s45, s67));

        char* tb = zblob + (size_t)(r >> 6) * 16384;
        const int rowp = r & 63;
#pragma unroll
        for (int cg = 0; cg < 8; ++cg) {
            short8v hv, lv;
#pragma unroll
            for (int e = 0; e < 8; ++e) {
                float f = fv[cg * 8 + e];
                unsigned short hb = f2bf_rne(f);
                float hf = __uint_as_float((unsigned)hb << 16);
                hv[e] = (short)hb;
                lv[e] = (short)f2bf_rne(f - hf);
            }
            *(short8v*)(tb + rowp * 128 + cg * 16) = hv;
            *(short8v*)(tb + 8192 + rowp * 128 + cg * 16) = lv;
        }
    }
}

// stage one 33.8KB emb tile image into LDS, 256-thread version (pass 2)
#define STAGE_EMB(DSTBASE, TILE)                                                  \
    {                                                                             \
        const char* gsrc = blob + (size_t)(TILE) * BLOB_TILE;                     \
        char* ldst = (DSTBASE) + ((tid >> 6) << 10);                              \
        const char* g = gsrc + tid * 16;                                          \
        _Pragma("unroll")                                                         \
        for (int q = 0; q < 8; ++q)                                               \
            gload_lds16(g + q * 4096, ldst + q * 4096);                           \
        if (tid < 64) gload_lds16(gsrc + 32768 + (tid & 63) * 16,                 \
                                  (DSTBASE) + 32768);                             \
    }

// 512-thread version (pass 1): each wave stages its 4KB chunk
#define STAGE512(DSTBASE, TILE)                                                   \
    {                                                                             \
        const char* gsrc = blob + (size_t)(TILE) * BLOB_TILE;                     \
        char* ldst = (DSTBASE) + ((tid >> 6) << 12);                              \
        const char* g = gsrc + ((tid >> 6) << 12) + (tid & 63) * 16;              \
        _Pragma("unroll")                                                         \
        for (int q = 0; q < 4; ++q)                                               \
            gload_lds16(g + q * 1024, ldst + q * 1024);                           \
        if (tid < 64) gload_lds16(gsrc + 32768 + (tid & 63) * 16,                 \
                                  (DSTBASE) + 32768);                             \
    }

// ---- pass 1 (frozen at its validated best): 8 waves x 16 rows, dbuf, 1 barrier/iter.
__global__ __launch_bounds__(512) void k_pass1(
    const char* __restrict__ zblob, const char* __restrict__ blob,
    const float* __restrict__ zz,
    float* __restrict__ Zpart, float* __restrict__ S1part,
    float* __restrict__ dmpart, int* __restrict__ impart)
{
    __shared__ __align__(16) char smem[2 * BLOB_TILE];

    const int tid = threadIdx.x;
    const int panel = blockIdx.x >> 2;      // 128 panels x 128 rows
    const int ks = blockIdx.x & 3;
    const int n0 = panel * 128;

    const int ln = tid & 63, wv = tid >> 6;
    const int lr = ln & 15, lg = ln >> 4;

    short8v Ah[2], Al[2];
    {
        const int p64 = (n0 >> 6) + (wv >> 2);
        const int rowp = (wv & 3) * 16 + lr;
        const char* tb = zblob + (size_t)p64 * 16384;
#pragma unroll
        for (int s = 0; s < 2; ++s) {
            const int byt = rowp * 128 + s * 64 + lg * 16;
            Ah[s] = *(const short8v*)(tb + byt);
            Al[s] = *(const short8v*)(tb + 8192 + byt);
        }
    }
    float zzr[4];
#pragma unroll
    for (int rg = 0; rg < 4; ++rg)
        zzr[rg] = zz[n0 + wv * 16 + lg * 4 + rg];

    STAGE512(smem, ks * 16);    // prologue: stage tile 0 into buf 0

    float Zp[4] = {0.f, 0.f, 0.f, 0.f}, S1p[4] = {0.f, 0.f, 0.f, 0.f};
    float dmin[4] = {FLT_MAX, FLT_MAX, FLT_MAX, FLT_MAX};
    int imin[4] = {0, 0, 0, 0};

    for (int it = 0; it < 16; ++it) {
        const int kbase = ks * 2048 + it * 128;
        __syncthreads();   // buf[it&1] staged (vmcnt drained before barrier)
        const char* bb = smem + (it & 1) * BLOB_TILE;
        if (it < 15) STAGE512(smem + ((it + 1) & 1) * BLOB_TILE, ks * 16 + it + 1);

        f32x4 acc[8];
#pragma unroll
        for (int f = 0; f < 8; ++f) { f32x4 zv = {0.f, 0.f, 0.f, 0.f}; acc[f] = zv; }

#pragma unroll
        for (int f = 0; f < 8; ++f) {
            const int rr = f * 16 + lr;
            const int sw2 = (rr & 7) << 4;
            short8v Bh[2], Bl[2];
#pragma unroll
            for (int s = 0; s < 2; ++s) {
                const int byt = (rr * 128 + s * 64 + lg * 16) ^ sw2;
                Bh[s] = *(const short8v*)(bb + byt);
                Bl[s] = *(const short8v*)(bb + 16384 + byt);
            }
#pragma unroll
            for (int s = 0; s < 2; ++s) {
                acc[f] = __builtin_amdgcn_mfma_f32_16x16x32_bf16(Ah[s], Bh[s], acc[f], 0, 0, 0);
                acc[f] = __builtin_amdgcn_mfma_f32_16x16x32_bf16(Ah[s], Bl[s], acc[f], 0, 0, 0);
                acc[f] = __builtin_amdgcn_mfma_f32_16x16x32_bf16(Al[s], Bh[s], acc[f], 0, 0, 0);
                acc[f] = __builtin_amdgcn_mfma_f32_16x16x32_bf16(Al[s], Bl[s], acc[f], 0, 0, 0);
            }
        }

#pragma unroll
        for (int f = 0; f < 8; ++f) {
            const float e2v = *(const float*)(bb + 32768 + (f * 16 + lr) * 4);
            const float c2 = *(const float*)(bb + 33280 + (f * 16 + lr) * 4);
            const int kk = kbase + f * 16 + lr;
#pragma unroll
            for (int rg = 0; rg < 4; ++rg) {
                const float sdot = acc[f][rg];
                const float t = fmaf(sdot, C200L2E, -c2);
                const float ex = __builtin_amdgcn_exp2f(t);
                Zp[rg] += ex;
                S1p[rg] = fmaf(t, ex, S1p[rg]);
                const float pre = __fadd_rn(zzr[rg], e2v);
                const float dnp = fmaf(-2.f, sdot, pre);
                if (dnp < dmin[rg]) { dmin[rg] = dnp; imin[rg] = kk; }
            }
        }
    }

    // reduce across the 16 lr lanes; lex tiebreak (min d, then min idx)
#pragma unroll
    for (int msk = 1; msk < 16; msk <<= 1) {
#pragma unroll
        for (int rg = 0; rg < 4; ++rg) {
            float d2 = __shfl_xor(dmin[rg], msk, 16);
            int i2 = __shfl_xor(imin[rg], msk, 16);
            float Z2 = __shfl_xor(Zp[rg], msk, 16);
            float s2 = __shfl_xor(S1p[rg], msk, 16);
            if (d2 < dmin[rg] || (d2 == dmin[rg] && i2 < imin[rg])) {
                dmin[rg] = d2; imin[rg] = i2;
            }
            Zp[rg] += Z2;
            S1p[rg] += s2;
        }
    }
    if (lr == 0) {
#pragma unroll
        for (int rg = 0; rg < 4; ++rg) {
            const int n = n0 + wv * 16 + lg * 4 + rg;
            Zpart[ks * 16384 + n] = Zp[rg];
            S1part[ks * 16384 + n] = S1p[rg];
            dmpart[ks * 16384 + n] = dmin[rg];
            impart[ks * 16384 + n] = imin[rg];
        }
    }
}

__global__ __launch_bounds__(256) void k_rowred(
    const float* __restrict__ Zpart, const float* __restrict__ S1part,
    const float* __restrict__ dmpart, const int* __restrict__ impart,
    float* __restrict__ invZ, int* __restrict__ minidx,
    float* __restrict__ out_idx, double* __restrict__ pse_sum)
{
    const int n = blockIdx.x * 256 + threadIdx.x;
    float Z = __fadd_rn(__fadd_rn(Zpart[n], Zpart[16384 + n]),
                        __fadd_rn(Zpart[32768 + n], Zpart[49152 + n]));
    float S1 = __fadd_rn(__fadd_rn(S1part[n], S1part[16384 + n]),
                         __fadd_rn(S1part[32768 + n], S1part[49152 + n]));
    float dm = dmpart[n];
    int im = impart[n];
#pragma unroll
    for (int ksp = 1; ksp < 4; ++ksp) {
        float d2 = dmpart[ksp * 16384 + n];
        int i2 = impart[ksp * 16384 + n];
        if (d2 < dm || (d2 == dm && i2 < im)) { dm = d2; im = i2; }
    }
    minidx[n] = im;
    out_idx[n] = (float)im;
    float iz = 1.0f / Z;
    invZ[n] = iz;
    double h = log((double)Z) - LN2 * (double)S1 * (double)iz;
#pragma unroll
    for (int m = 32; m > 0; m >>= 1) h += __shfl_xor(h, m, 64);
    if ((threadIdx.x & 63) == 0) atomicAdd(pse_sum, h);
}

// ---- pass 2 v7 (k-major, m=1): block = k-tile kt (128 codes) x 1024-row n
// range; wave owns 16 rows/iter, 16 iters; acc[8] (32 VGPR) + per-lane acck
// register accumulation; 3-term MFMA; one shfl+atomic round at the end.
// Barrier-free after the single staging barrier.
__global__ __launch_bounds__(256) void k_pass2(
    const char* __restrict__ zblob, const char* __restrict__ blob,
    const float* __restrict__ invZ, float* __restrict__ avg_acc)
{
    __shared__ __align__(16) char smem[BLOB_TILE + 4096];
    float* izAll = (float*)(smem + BLOB_TILE);   // [1024] f32

    const int tid = threadIdx.x;
    const int kt = blockIdx.x & 63;
    const int ns = blockIdx.x >> 6;      // 0..15: rows ns*1024 .. +1023
    const int ln = tid & 63, wv = tid >> 6;
    const int lr = ln & 15, lg = ln >> 4;

    STAGE_EMB(smem, kt);
    gload_lds16((const char*)(invZ + ns * 1024) + tid * 16,
                (char*)izAll + (wv << 10));
    __syncthreads();     // only barrier in the kernel

    float c2v[8];
#pragma unroll
    for (int f = 0; f < 8; ++f)
        c2v[f] = *(const float*)(smem + 33280 + (f * 16 + lr) * 4);

    float acck[8] = {0.f, 0.f, 0.f, 0.f, 0.f, 0.f, 0.f, 0.f};

#pragma unroll 1
    for (int it = 0; it < 16; ++it) {
        // wave's 16 rows this iter: n0 = ns*1024 + it*64 + wv*16
        const char* tb = zblob + (size_t)(ns * 16 + it) * 16384;
        const int rowp = wv * 16 + lr;
        short8v Ah[2], Al[2];
#pragma unroll
        for (int s = 0; s < 2; ++s) {
            const int byt = rowp * 128 + s * 64 + lg * 16;
            Ah[s] = *(const short8v*)(tb + byt);
            Al[s] = *(const short8v*)(tb + 8192 + byt);
        }
        float4 iz = *(const float4*)&izAll[it * 64 + wv * 16 + lg * 4];
        float izr[4] = {iz.x, iz.y, iz.z, iz.w};

        f32x4 acc[8];
#pragma unroll
        for (int f = 0; f < 8; ++f) { f32x4 zv = {0.f, 0.f, 0.f, 0.f}; acc[f] = zv; }

#pragma unroll
        for (int f = 0; f < 8; ++f) {
            const int rr = f * 16 + lr;
            const int sw2 = (rr & 7) << 4;
            short8v Bh[2], Bl[2];
#pragma unroll
            for (int s = 0; s < 2; ++s) {
                const int byt = (rr * 128 + s * 64 + lg * 16) ^ sw2;
                Bh[s] = *(const short8v*)(smem + byt);
                Bl[s] = *(const short8v*)(smem + 16384 + byt);
            }
#pragma unroll
            for (int s = 0; s < 2; ++s) {
                acc[f] = __builtin_amdgcn_mfma_f32_16x16x32_bf16(Ah[s], Bh[s], acc[f], 0, 0, 0);
                acc[f] = __builtin_amdgcn_mfma_f32_16x16x32_bf16(Ah[s], Bl[s], acc[f], 0, 0, 0);
                acc[f] = __builtin_amdgcn_mfma_f32_16x16x32_bf16(Al[s], Bh[s], acc[f], 0, 0, 0);
            }
        }

#pragma unroll
        for (int f = 0; f < 8; ++f) {
#pragma unroll
            for (int rg = 0; rg < 4; ++rg) {
                const float t = fmaf(acc[f][rg], C200L2E, -c2v[f]);
                const float ex = __builtin_amdgcn_exp2f(t);
                acck[f] = fmaf(ex, izr[rg], acck[f]);
            }
        }
    }

    // one reduce + atomic round per wave
#pragma unroll
    for (int f = 0; f < 8; ++f) {
        float cs = acck[f];
        cs += __shfl_xor(cs, 16, 64);
        cs += __shfl_xor(cs, 32, 64);
        if (lg == 0) atomicAdd(&avg_acc[kt * 128 + f * 16 + lr], cs);
    }
}

// gather quantized output + per-block loss partial; 4 elements/thread
__global__ __launch_bounds__(256) void k_quant(
    const float* __restrict__ z, const float* __restrict__ emb,
    const int* __restrict__ minidx, float* __restrict__ out,
    double* __restrict__ loss_part)
{
    __shared__ float lred[4];
    const int o4 = (blockIdx.x * 256 + threadIdx.x) * 4;
    const int nb = ((o4 >> 16) << 10) + (o4 & 1023);
    const int c = (o4 >> 10) & 63;
    const float4 zv = *(const float4*)(z + o4);
    const int i0 = minidx[nb], i1 = minidx[nb + 1];
    const int i2 = minidx[nb + 2], i3 = minidx[nb + 3];
    float4 ev;
    ev.x = emb[i0 * 64 + c];
    ev.y = emb[i1 * 64 + c];
    ev.z = emb[i2 * 64 + c];
    ev.w = emb[i3 * 64 + c];
    *(float4*)(out + o4) = ev;
    const float dx = ev.x - zv.x, dy = ev.y - zv.y;
    const float dz = ev.z - zv.z, dw = ev.w - zv.w;
    float sq = dx * dx + dy * dy + dz * dz + dw * dw;
#pragma unroll
    for (int m = 32; m > 0; m >>= 1) sq += __shfl_xor(sq, m, 64);
    if ((threadIdx.x & 63) == 0) lred[threadIdx.x >> 6] = sq;
    __syncthreads();
    if (threadIdx.x == 0)
        loss_part[blockIdx.x] = (double)lred[0] + (double)lred[1]
                              + (double)lred[2] + (double)lred[3];
}

__global__ __launch_bounds__(256) void k_final(
    const float* __restrict__ avg_acc, const double* __restrict__ pse_sum,
    const double* __restrict__ loss_part, float* __restrict__ out)
{
    __shared__ double red[256];
    const int tid = threadIdx.x;

    double lsum = 0.0;
    for (int k = tid; k < 1024; k += 256) lsum += loss_part[k];
    red[tid] = lsum;
    __syncthreads();
    for (int s = 128; s > 0; s >>= 1) {
        if (tid < s) red[tid] += red[tid + s];
        __syncthreads();
    }
    double ltot = red[0];
    __syncthreads();

    double local = 0.0;
    for (int k = tid; k < 8192; k += 256) {
        float p = avg_acc[k] * (1.0f / 16384.0f);
        float cl = fmaxf(p, 1e-5f);
        local += (double)(-p * logf(cl));
    }
    red[tid] = local;
    __syncthreads();
    for (int s = 128; s > 0; s >>= 1) {
        if (tid < s) red[tid] += red[tid + s];
        __syncthreads();
    }
    if (tid == 0) {
        double ce = red[0];
        double pse = pse_sum[0] / 16384.0;
        out[1048576] = (float)(1.25 * ltot / 1048576.0);
        out[1048577] = (float)(pse - ce);
    }
}

extern "C" void kernel_launch(void* const* d_in, const int* in_sizes, int n_in,
                              void* d_out, int out_size, void* d_ws, size_t ws_size,
                              hipStream_t stream) {
    const float* z = (const float*)d_in[0];
    const float* emb = (const float*)d_in[1];
    float* out = (float*)d_out;
    char* ws = (char*)d_ws;
    char* blob = ws + OFF_BLOB;
    float* invZ = (float*)(ws + OFF_INVZ);
    int* minidx = (int*)(ws + OFF_MINIDX);
    float* avg_acc = (float*)(ws + OFF_AVG);
    double* pse_sum = (double*)(ws + OFF_PSE);
    float* Zpart = (float*)(ws + OFF_ZPART);
    float* S1part = (float*)(ws + OFF_S1PART);
    float* dmpart = (float*)(ws + OFF_DMPART);
    int* impart = (int*)(ws + OFF_IMPART);
    double* loss_part = (double*)(ws + OFF_LOSSP);
    float* zz = (float*)(ws + OFF_ZZ);
    // z_blob scratch lives in d_out's quantized region (exactly 4 MB);
    // k_quant overwrites it afterwards (stream-ordered).
    char* zblob = (char*)d_out;

    // zero avg_acc + pse_sum every launch (no cross-replay state)
    hipMemsetAsync(ws + OFF_AVG, 0, 32768 + 16, stream);

    k_prep<<<96, 256, 0, stream>>>(emb, z, blob, zblob, zz);
    k_pass1<<<512, 512, 0, stream>>>(zblob, blob, zz, Zpart, S1part, dmpart, impart);
    k_rowred<<<64, 256, 0, stream>>>(Zpart, S1part, dmpart, impart,
                                     invZ, minidx, out + 1048578, pse_sum);
    k_pass2<<<1024, 256, 0, stream>>>(zblob, blob, invZ, avg_acc);
    k_quant<<<1024, 256, 0, stream>>>(z, emb, minidx, out, loss_part);
    k_final<<<1, 256, 0, stream>>>(avg_acc, pse_sum, loss_part, out);
}